// Round 1
// baseline (255.568 us; speedup 1.0000x reference)
//
#include <hip/hip_runtime.h>
#include <math.h>

// MS-SSIM loss, fp32, (32,3,384,384), 5 scales, win=11 sigma=1.5, VALID.
// R9: occupancy push. R8 was latency-bound at a hard 50% occupancy cap:
// 8-row accumulator file (64 VGPR) + QQ + staging = ~128 regs total
// (VGPR 48 + AGPRs on the unified file), launch_bounds(256,4) -> 4
// waves/SIMD. VALUBusy 52% ~= occupancy 47.7%: resident waves issue,
// but half the cycles all 4 are stalled on HBM row loads / dep chains.
// Fix: 4 rows/wave (acc file 32 regs, total ~75) + launch_bounds(256,6)
// -> 6 waves/SIMD. vblur FMA count is per-output-row invariant (4 acc x
// 11 taps = 44 pk_fma/row, same as 8x11/8); only row overhead grows
// (14 loads/4 rows vs 18/8, ~+7% VALU) for +50% issue slots.
// Grid: 16 output rows/block -> 130 tiles/img.

namespace {

constexpr int NIMG = 96;            // B*C = 32*3
constexpr float TWO_C1 = 13.005f;   // 2*(0.01*255)^2
constexpr float TWO_C2 = 117.045f;  // 2*(0.03*255)^2

// gauss(11, sigma=1.5), normalized (matches expf path to fp32 ulp).
__device__ constexpr float GW[11] = {
    0.00102838f, 0.00759875f, 0.03600077f, 0.10936070f, 0.21300553f,
    0.26601172f,
    0.21300553f, 0.10936070f, 0.03600077f, 0.00759875f, 0.00102838f};

typedef float f2 __attribute__((ext_vector_type(2)));

// ---- VOP3P packed fp32 with op_sel variants ----
// op_sel[i]: half feeding LOW result (0=lo); op_sel_hi[i]: half feeding HIGH.
__device__ __forceinline__ f2 pk_mul(f2 a, f2 b) {
  f2 d;
  asm("v_pk_mul_f32 %0, %1, %2" : "=v"(d) : "v"(a), "v"(b));
  return d;
}
// d = a * splat_lo(b)  (init of hblur chain, j=0 even term)
__device__ __forceinline__ f2 pk_mul_s1lo(f2 a, f2 b) {
  f2 d;
  asm("v_pk_mul_f32 %0, %1, %2 op_sel:[0,0] op_sel_hi:[1,0]"
      : "=v"(d) : "v"(a), "v"(b));
  return d;
}
// d += splat_lo(q) * p   (vblur tap: weight splat from pair reg)
__device__ __forceinline__ void fma_w(f2& d, f2 q, f2 p) {
  asm("v_pk_fma_f32 %0, %1, %2, %0 op_sel:[0,0,0] op_sel_hi:[0,1,1]"
      : "+v"(d) : "v"(q), "v"(p));
}
// d += q * splat_lo(t)
__device__ __forceinline__ void fma_nl(f2& d, f2 q, f2 t) {
  asm("v_pk_fma_f32 %0, %1, %2, %0 op_sel:[0,0,0] op_sel_hi:[1,0,1]"
      : "+v"(d) : "v"(q), "v"(t));
}
// d += q * splat_hi(t)
__device__ __forceinline__ void fma_nh(f2& d, f2 q, f2 t) {
  asm("v_pk_fma_f32 %0, %1, %2, %0 op_sel:[0,1,0] op_sel_hi:[1,1,1]"
      : "+v"(d) : "v"(q), "v"(t));
}
// d += swap(q) * splat_lo(t)
__device__ __forceinline__ void fma_sl(f2& d, f2 q, f2 t) {
  asm("v_pk_fma_f32 %0, %1, %2, %0 op_sel:[1,0,0] op_sel_hi:[0,0,1]"
      : "+v"(d) : "v"(q), "v"(t));
}
// d += swap(q) * splat_hi(t)
__device__ __forceinline__ void fma_sh(f2& d, f2 q, f2 t) {
  asm("v_pk_fma_f32 %0, %1, %2, %0 op_sel:[1,1,0] op_sel_hi:[0,1,1]"
      : "+v"(d) : "v"(q), "v"(t));
}

// lane i <- lane i+1 (wave_shl:1); lane 63 gets 0. HW-verified (R5-R7).
__device__ __forceinline__ float wshl1(float v) {
  return __int_as_float(__builtin_amdgcn_mov_dpp(
      __float_as_int(v), 0x130, 0xF, 0xF, true));
}
__device__ __forceinline__ f2 wshl1v(f2 v) {
  f2 r;
  r.x = wshl1(v.x);
  r.y = wshl1(v.y);
  return r;
}

struct SPtrs {
  const float* x[5];   // s=0: X0; s>=1: U plane (x+y)
  const float* y[5];   // s=0: Y0; s>=1: W plane (x-y)
};

template <bool BASE, bool CLAMP>
__device__ __forceinline__ void vblur(const f2* __restrict__ PA,
                                      const f2* __restrict__ PB, int row0,
                                      int W2, int H, int cp, f2 (&AU)[4],
                                      f2 (&AW)[4], f2 (&BU)[4], f2 (&BW)[4],
                                      const f2 (&QQ)[6]) {
#pragma unroll
  for (int j = 0; j < 14; ++j) {
    int rin = row0 + j;
    if (CLAMP) rin = rin < H - 1 ? rin : H - 1;
    f2 pa = PA[(size_t)rin * W2 + cp];
    f2 pb = PB[(size_t)rin * W2 + cp];
    f2 Pu, Pw;
    if (BASE) { Pu = pa + pb; Pw = pa - pb; }   // u, w col-pairs
    else      { Pu = pa;      Pw = pb;      }
    f2 Qu = pk_mul(Pu, Pu), Qw = pk_mul(Pw, Pw);
#pragma unroll
    for (int i = 0; i < 4; ++i) {
      const int k = j - i;
      if (k >= 0 && k <= 10) {
        const int qi = k <= 5 ? k : 10 - k;     // G[k] = QQ[qi].x
        fma_w(AU[i], QQ[qi], Pu);
        fma_w(AW[i], QQ[qi], Pw);
        fma_w(BU[i], QQ[qi], Qu);
        fma_w(BW[i], QQ[qi], Qw);
      }
    }
  }
}

// Tile: 64 lanes x 2 cols = 128 input cols -> up to 118 outputs; 4 output
// rows per wave, 4 waves stacked = 16 rows/block.
// Grid/img: s0 4x24=96, s1 2x12=24, s2 6, s3 3, s4 1 (total 130).
__global__ __launch_bounds__(256, 6) void ssim_all(SPtrs sp,
                                                   float* __restrict__ acc) {
  __shared__ float red[2][4];

  const int tile = blockIdx.x;
  int s;
  if (tile < 96) s = 0;
  else if (tile < 120) s = 1;
  else if (tile < 126) s = 2;
  else if (tile < 129) s = 3;
  else s = 4;
  const int tstart[5] = {0, 96, 120, 126, 129};
  const int HH[5] = {384, 192, 96, 48, 24};
  const int NTX[5] = {4, 2, 1, 1, 1};
  const int TWM[5] = {94, 92, 86, 38, 14};
  const int lt = tile - tstart[s];
  const int H = HH[s], W = H, OH = H - 10, OW = W - 10, W2 = W >> 1;
  const int tx = lt % NTX[s], by = lt / NTX[s];
  const int x0 = tx * TWM[s];
  const int tw = (TWM[s] < OW - x0) ? TWM[s] : OW - x0;
  const int img = blockIdx.z;
  const f2* PA = (const f2*)sp.x[s] + (size_t)img * H * W2;
  const f2* PB = (const f2*)sp.y[s] + (size_t)img * H * W2;

  const int t = threadIdx.x;
  const int lane = t & 63, wv = t >> 6;
  int cp = (x0 >> 1) + lane;
  cp = cp < W2 - 1 ? cp : W2 - 1;
  const int row0 = by * 16 + wv * 4;

  // Weight pairs QQ[n] = (G[n], G[n-1]), G[-1]=0. All other weight forms
  // derived via op_sel (splat-lo / swap) using G[k] = G[10-k].
  f2 QQ[6];
  QQ[0].x = GW[0]; QQ[0].y = 0.f;
#pragma unroll
  for (int n = 1; n < 6; ++n) { QQ[n].x = GW[n]; QQ[n].y = GW[n - 1]; }

  float ssim_s = 0.f, cs_s = 0.f;

  if (row0 < OH) {
    f2 AU[4] = {}, AW[4] = {}, BU[4] = {}, BW[4] = {};
    const bool noclamp = (row0 + 13 <= H - 1);
    if (s == 0) {
      if (noclamp) vblur<true, false>(PA, PB, row0, W2, H, cp, AU, AW, BU, BW, QQ);
      else         vblur<true, true >(PA, PB, row0, W2, H, cp, AU, AW, BU, BW, QQ);
    } else {
      if (noclamp) vblur<false, false>(PA, PB, row0, W2, H, cp, AU, AW, BU, BW, QQ);
      else         vblur<false, true >(PA, PB, row0, W2, H, cp, AU, AW, BU, BW, QQ);
    }

    // hblur: 2 outputs/lane, 5 two-col shift steps.
    // O.x = sum_k G[k]*V[2c+k], O.y = sum_k G[k]*V[2c+1+k]; contribution of
    // t_j=(e,o)=(V[2c+2j],V[2c+2j+1]): (G[2j],G[2j-1])*e + (G[2j+1],G[2j])*o.
    auto hb = [&QQ](f2 tt) -> f2 {
      f2 h = pk_mul_s1lo(QQ[0], tt);   // j=0: (G0,0)*e
      fma_nh(h, QQ[1], tt);            // j=0: (G1,G0)*o
      tt = wshl1v(tt);
      fma_nl(h, QQ[2], tt);            // j=1: (G2,G1)*e
      fma_nh(h, QQ[3], tt);            // j=1: (G3,G2)*o
      tt = wshl1v(tt);
      fma_nl(h, QQ[4], tt);            // j=2: (G4,G3)*e
      fma_nh(h, QQ[5], tt);            // j=2: (G5,G4)*o
      tt = wshl1v(tt);
      fma_sl(h, QQ[5], tt);            // j=3: (G6,G5)=(G4,G5)=swap(QQ5)
      fma_sh(h, QQ[4], tt);            // j=3: (G7,G6)=(G3,G4)=swap(QQ4)
      tt = wshl1v(tt);
      fma_sl(h, QQ[3], tt);            // j=4: (G8,G7)=swap(QQ3)
      fma_sh(h, QQ[2], tt);            // j=4: (G9,G8)=swap(QQ2)
      tt = wshl1v(tt);
      fma_sl(h, QQ[1], tt);            // j=5: (G10,G9)=swap(QQ1)
      fma_sh(h, QQ[0], tt);            // j=5: (0,G10)=swap(QQ0)
      return h;
    };

    const bool vx = (2 * lane) < tw;
    const bool vy = (2 * lane + 1) < tw;
#pragma unroll
    for (int i = 0; i < 4; ++i) {
      if (row0 + i < OH) {
        f2 bU = hb(AU[i]), bW = hb(AW[i]);
        f2 bU2 = hb(BU[i]), bW2 = hb(BW[i]);
        f2 m2u = pk_mul(bU, bU), m2w = pk_mul(bW, bW);
        f2 Pm = m2u - m2w;           // 4*mu1*mu2
        f2 Qm = m2u + m2w;           // 2*(mu1^2+mu2^2)
        f2 Am = bU2 - bW2;           // 4*E[xy]
        f2 Bm = bU2 + bW2;           // 2*(E[xx]+E[yy])
        float csx = (Am.x - Pm.x + TWO_C2) *
                    __builtin_amdgcn_rcpf(Bm.x - Qm.x + TWO_C2);
        float lx = (Pm.x + TWO_C1) * __builtin_amdgcn_rcpf(Qm.x + TWO_C1);
        float csy = (Am.y - Pm.y + TWO_C2) *
                    __builtin_amdgcn_rcpf(Bm.y - Qm.y + TWO_C2);
        float ly = (Pm.y + TWO_C1) * __builtin_amdgcn_rcpf(Qm.y + TWO_C1);
        if (vx) { cs_s += csx; ssim_s += lx * csx; }
        if (vy) { cs_s += csy; ssim_s += ly * csy; }
      }
    }
  }

  // ---- reduce: wave shuffle -> LDS -> 2 atomics/block ----
#pragma unroll
  for (int off = 32; off > 0; off >>= 1) {
    ssim_s += __shfl_down(ssim_s, off);
    cs_s += __shfl_down(cs_s, off);
  }
  if (lane == 0) { red[0][wv] = ssim_s; red[1][wv] = cs_s; }
  __syncthreads();
  if (t == 0) {
    atomicAdd(&acc[(2 * s + 0) * NIMG + img],
              red[0][0] + red[0][1] + red[0][2] + red[0][3]);
    atomicAdd(&acc[(2 * s + 1) * NIMG + img],
              red[1][0] + red[1][1] + red[1][2] + red[1][3]);
  }
}

// Barrier-free pyramid producing u=x+y, w=x-y planes at levels 1..4.
// Each wave owns one 16x16 source tile -> 8x8 L1, 4x4 L2, 2x2 L3, 1x1 L4
// via shfl_xor 2x2 reductions. Block(0,*) of img 0 zeroes accumulators.
__global__ __launch_bounds__(256) void pyramid_kernel(
    const float* __restrict__ X, const float* __restrict__ Y,
    float* __restrict__ u1, float* __restrict__ w1,
    float* __restrict__ u2, float* __restrict__ w2,
    float* __restrict__ u3, float* __restrict__ w3,
    float* __restrict__ u4, float* __restrict__ w4,
    float* __restrict__ acc) {
  const int img = blockIdx.y;
  const int t = threadIdx.x;
  if (blockIdx.x == 0 && img == 0) {
    for (int i = t; i < 10 * NIMG; i += 256) acc[i] = 0.f;
  }
  const int wv = t >> 6, lane = t & 63;
  const int tidx = blockIdx.x * 4 + wv;     // 0..575
  const int tx = tidx % 24, ty = tidx / 24;
  const int r = lane >> 3, c = lane & 7;    // 8x8 within wave

  const float* Xs = X + (size_t)img * 384 * 384;
  const float* Ys = Y + (size_t)img * 384 * 384;
  float* o1[2] = {u1 + (size_t)img * 192 * 192, w1 + (size_t)img * 192 * 192};
  float* o2[2] = {u2 + (size_t)img * 96 * 96,   w2 + (size_t)img * 96 * 96};
  float* o3[2] = {u3 + (size_t)img * 48 * 48,   w3 + (size_t)img * 48 * 48};
  float* o4[2] = {u4 + (size_t)img * 24 * 24,   w4 + (size_t)img * 24 * 24};

  int gr = ty * 16 + 2 * r, gc = tx * 16 + 2 * c;
  float2 xu = *(const float2*)&Xs[(size_t)gr * 384 + gc];
  float2 xv = *(const float2*)&Xs[(size_t)(gr + 1) * 384 + gc];
  float2 yu = *(const float2*)&Ys[(size_t)gr * 384 + gc];
  float2 yv = *(const float2*)&Ys[(size_t)(gr + 1) * 384 + gc];
  float l1x = 0.25f * (xu.x + xu.y + xv.x + xv.y);
  float l1y = 0.25f * (yu.x + yu.y + yv.x + yv.y);
  float lv[2] = {l1x + l1y, l1x - l1y};     // u, w at level 1

#pragma unroll
  for (int ch = 0; ch < 2; ++ch) {
    float l1 = lv[ch];
    o1[ch][(size_t)(ty * 8 + r) * 192 + tx * 8 + c] = l1;

    float l2 = l1 + __shfl_xor(l1, 1);
    l2 = 0.25f * (l2 + __shfl_xor(l2, 8));
    if ((r & 1) == 0 && (c & 1) == 0)
      o2[ch][(size_t)(ty * 4 + (r >> 1)) * 96 + tx * 4 + (c >> 1)] = l2;

    float l3 = l2 + __shfl_xor(l2, 2);
    l3 = 0.25f * (l3 + __shfl_xor(l3, 16));
    if ((r & 3) == 0 && (c & 3) == 0)
      o3[ch][(size_t)(ty * 2 + (r >> 2)) * 48 + tx * 2 + (c >> 2)] = l3;

    float l4 = l3 + __shfl_xor(l3, 4);
    l4 = 0.25f * (l4 + __shfl_xor(l4, 32));
    if (lane == 0) o4[ch][(size_t)ty * 24 + tx] = l4;
  }
}

// acc layout: acc[s*2+0][img] = ssim sum, acc[s*2+1][img] = cs sum.
__global__ void final_kernel(const float* __restrict__ acc,
                             float* __restrict__ out) {
  __shared__ float prods[NIMG];
  const float wts[5] = {0.0448f, 0.2856f, 0.3001f, 0.2363f, 0.1333f};
  const float inv_npix[5] = {1.f / (374.f * 374.f), 1.f / (182.f * 182.f),
                             1.f / (86.f * 86.f),  1.f / (38.f * 38.f),
                             1.f / (14.f * 14.f)};
  int t = threadIdx.x;
  if (t < NIMG) {
    float p = 1.f;
#pragma unroll
    for (int s = 0; s < 5; ++s) {
      float sum = (s < 4) ? acc[(s * 2 + 1) * NIMG + t]
                          : acc[(s * 2 + 0) * NIMG + t];
      float m = sum * inv_npix[s];
      m = m > 0.f ? m : 0.f;
      p *= powf(m, wts[s]);
    }
    prods[t] = p;
  }
  __syncthreads();
  if (t == 0) {
    float s = 0.f;
    for (int i = 0; i < NIMG; ++i) s += prods[i];
    out[0] = 1.f - s / (float)NIMG;
  }
}

}  // namespace

extern "C" void kernel_launch(void* const* d_in, const int* in_sizes, int n_in,
                              void* d_out, int out_size, void* d_ws,
                              size_t ws_size, hipStream_t stream) {
  const float* X0 = (const float*)d_in[0];
  const float* Y0 = (const float*)d_in[1];
  float* out = (float*)d_out;
  float* ws = (float*)d_ws;

  const size_t L1 = (size_t)NIMG * 192 * 192;
  const size_t L2 = (size_t)NIMG * 96 * 96;
  const size_t L3 = (size_t)NIMG * 48 * 48;
  const size_t L4 = (size_t)NIMG * 24 * 24;

  float* u1 = ws;
  float* u2 = u1 + L1;
  float* u3 = u2 + L2;
  float* u4 = u3 + L3;
  float* w1 = u4 + L4;
  float* w2 = w1 + L1;
  float* w3 = w2 + L2;
  float* w4 = w3 + L3;
  float* acc = w4 + L4;  // 5*2*96 floats

  pyramid_kernel<<<dim3(144, NIMG), dim3(256), 0, stream>>>(
      X0, Y0, u1, w1, u2, w2, u3, w3, u4, w4, acc);

  SPtrs sp;
  sp.x[0] = X0; sp.x[1] = u1; sp.x[2] = u2; sp.x[3] = u3; sp.x[4] = u4;
  sp.y[0] = Y0; sp.y[1] = w1; sp.y[2] = w2; sp.y[3] = w3; sp.y[4] = w4;

  ssim_all<<<dim3(130, 1, NIMG), dim3(256), 0, stream>>>(sp, acc);

  final_kernel<<<dim3(1), dim3(128), 0, stream>>>(acc, out);
}

// Round 2
// 241.002 us; speedup vs baseline: 1.0604x; 1.0604x over previous
//
#include <hip/hip_runtime.h>
#include <math.h>

// MS-SSIM loss, fp32, (32,3,384,384), 5 scales, win=11 sigma=1.5, VALID.
// R10: latency fixes. R9 post-mortem: per-wave VALU issue fraction is
// ~13% in BOTH R8/R9 (VALUBusy ~= occupancy x 0.13) -> vblur's 28 global
// loads are fully serialized per j-iteration (~400cy stall vs ~40cy
// compute each); occupancy pushes don't help because extra waves bring
// extra halo work. Fixes:
//  (a) vblur: explicit depth-4 register prefetch (16 staging VGPRs,
//      launch_bounds(256,5) for headroom). Period -> max(44, L/4) cy,
//      per-wave issue ~0.44, x5 waves saturates SIMD.
//  (b) pyramid rewrite: ~100us at 1.4TB/s from float2/64B-segment loads
//      + scattered stores. Now 64x16 tile/wave, dwordx4 loads (256B
//      segments), float4 stores, u/w INTERLEAVED per col-pair
//      (u0,u1,w0,w1) -> also halves ssim_all's s>=1 load count.

namespace {

constexpr int NIMG = 96;            // B*C = 32*3
constexpr float TWO_C1 = 13.005f;   // 2*(0.01*255)^2
constexpr float TWO_C2 = 117.045f;  // 2*(0.03*255)^2

// gauss(11, sigma=1.5), normalized (matches expf path to fp32 ulp).
__device__ constexpr float GW[11] = {
    0.00102838f, 0.00759875f, 0.03600077f, 0.10936070f, 0.21300553f,
    0.26601172f,
    0.21300553f, 0.10936070f, 0.03600077f, 0.00759875f, 0.00102838f};

typedef float f2 __attribute__((ext_vector_type(2)));
typedef float f4 __attribute__((ext_vector_type(4)));

// ---- VOP3P packed fp32 with op_sel variants ----
// op_sel[i]: half feeding LOW result (0=lo); op_sel_hi[i]: half feeding HIGH.
__device__ __forceinline__ f2 pk_mul(f2 a, f2 b) {
  f2 d;
  asm("v_pk_mul_f32 %0, %1, %2" : "=v"(d) : "v"(a), "v"(b));
  return d;
}
// d = a * splat_lo(b)  (init of hblur chain, j=0 even term)
__device__ __forceinline__ f2 pk_mul_s1lo(f2 a, f2 b) {
  f2 d;
  asm("v_pk_mul_f32 %0, %1, %2 op_sel:[0,0] op_sel_hi:[1,0]"
      : "=v"(d) : "v"(a), "v"(b));
  return d;
}
// d += splat_lo(q) * p   (vblur tap: weight splat from pair reg)
__device__ __forceinline__ void fma_w(f2& d, f2 q, f2 p) {
  asm("v_pk_fma_f32 %0, %1, %2, %0 op_sel:[0,0,0] op_sel_hi:[0,1,1]"
      : "+v"(d) : "v"(q), "v"(p));
}
// d += q * splat_lo(t)
__device__ __forceinline__ void fma_nl(f2& d, f2 q, f2 t) {
  asm("v_pk_fma_f32 %0, %1, %2, %0 op_sel:[0,0,0] op_sel_hi:[1,0,1]"
      : "+v"(d) : "v"(q), "v"(t));
}
// d += q * splat_hi(t)
__device__ __forceinline__ void fma_nh(f2& d, f2 q, f2 t) {
  asm("v_pk_fma_f32 %0, %1, %2, %0 op_sel:[0,1,0] op_sel_hi:[1,1,1]"
      : "+v"(d) : "v"(q), "v"(t));
}
// d += swap(q) * splat_lo(t)
__device__ __forceinline__ void fma_sl(f2& d, f2 q, f2 t) {
  asm("v_pk_fma_f32 %0, %1, %2, %0 op_sel:[1,0,0] op_sel_hi:[0,0,1]"
      : "+v"(d) : "v"(q), "v"(t));
}
// d += swap(q) * splat_hi(t)
__device__ __forceinline__ void fma_sh(f2& d, f2 q, f2 t) {
  asm("v_pk_fma_f32 %0, %1, %2, %0 op_sel:[1,1,0] op_sel_hi:[0,1,1]"
      : "+v"(d) : "v"(q), "v"(t));
}

// lane i <- lane i+1 (wave_shl:1); lane 63 gets 0. HW-verified (R5-R7).
__device__ __forceinline__ float wshl1(float v) {
  return __int_as_float(__builtin_amdgcn_mov_dpp(
      __float_as_int(v), 0x130, 0xF, 0xF, true));
}
__device__ __forceinline__ f2 wshl1v(f2 v) {
  f2 r;
  r.x = wshl1(v.x);
  r.y = wshl1(v.y);
  return r;
}

struct SPtrs {
  const float* x0;
  const float* y0;
  const float* ip[4];  // levels 1..4, u/w interleaved (u0,u1,w0,w1)/colpair
};

// Depth-4 register-prefetched vertical blur. BASE: two f2 loads per row
// (X0,Y0 planes), u/w formed in-kernel. !BASE: ONE f4 load per row from
// the interleaved plane (Pu=v.xy, Pw=v.zw).
template <bool BASE, bool CLAMP>
__device__ __forceinline__ void vblur(const float* __restrict__ XP,
                                      const float* __restrict__ YP, int row0,
                                      int W2, int H, int cp, f2 (&AU)[4],
                                      f2 (&AW)[4], f2 (&BU)[4], f2 (&BW)[4],
                                      const f2 (&QQ)[6]) {
  const f2* PA = (const f2*)XP;
  const f2* PB = (const f2*)YP;
  const f4* PV = (const f4*)XP;
  f2 sa[4], sb[4];
  f4 sv[4];
#pragma unroll
  for (int j = 0; j < 4; ++j) {
    int rin = row0 + j;
    if (CLAMP) rin = rin < H - 1 ? rin : H - 1;
    if (BASE) {
      sa[j] = PA[(size_t)rin * W2 + cp];
      sb[j] = PB[(size_t)rin * W2 + cp];
    } else {
      sv[j] = PV[(size_t)rin * W2 + cp];
    }
  }
#pragma unroll
  for (int j = 0; j < 14; ++j) {
    f2 Pu, Pw;
    if (BASE) {
      f2 pa = sa[j & 3], pb = sb[j & 3];
      Pu = pa + pb;
      Pw = pa - pb;
    } else {
      f4 v = sv[j & 3];
      Pu.x = v.x; Pu.y = v.y;
      Pw.x = v.z; Pw.y = v.w;
    }
    if (j + 4 < 14) {   // prefetch 4 rows ahead (consumed-then-overwritten)
      int rin = row0 + j + 4;
      if (CLAMP) rin = rin < H - 1 ? rin : H - 1;
      if (BASE) {
        sa[j & 3] = PA[(size_t)rin * W2 + cp];
        sb[j & 3] = PB[(size_t)rin * W2 + cp];
      } else {
        sv[j & 3] = PV[(size_t)rin * W2 + cp];
      }
    }
    f2 Qu = pk_mul(Pu, Pu), Qw = pk_mul(Pw, Pw);
#pragma unroll
    for (int i = 0; i < 4; ++i) {
      const int k = j - i;
      if (k >= 0 && k <= 10) {
        const int qi = k <= 5 ? k : 10 - k;     // G[k] = QQ[qi].x
        fma_w(AU[i], QQ[qi], Pu);
        fma_w(AW[i], QQ[qi], Pw);
        fma_w(BU[i], QQ[qi], Qu);
        fma_w(BW[i], QQ[qi], Qw);
      }
    }
  }
}

// Tile: 64 lanes x 2 cols = 128 input cols -> up to 118 outputs; 4 output
// rows per wave, 4 waves stacked = 16 rows/block.
// Grid/img: s0 4x24=96, s1 2x12=24, s2 6, s3 3, s4 1 (total 130).
__global__ __launch_bounds__(256, 5) void ssim_all(SPtrs sp,
                                                   float* __restrict__ acc) {
  __shared__ float red[2][4];

  const int tile = blockIdx.x;
  int s;
  if (tile < 96) s = 0;
  else if (tile < 120) s = 1;
  else if (tile < 126) s = 2;
  else if (tile < 129) s = 3;
  else s = 4;
  const int tstart[5] = {0, 96, 120, 126, 129};
  const int HH[5] = {384, 192, 96, 48, 24};
  const int NTX[5] = {4, 2, 1, 1, 1};
  const int TWM[5] = {94, 92, 86, 38, 14};
  const int lt = tile - tstart[s];
  const int H = HH[s], W = H, OH = H - 10, OW = W - 10, W2 = W >> 1;
  const int tx = lt % NTX[s], by = lt / NTX[s];
  const int x0 = tx * TWM[s];
  const int tw = (TWM[s] < OW - x0) ? TWM[s] : OW - x0;
  const int img = blockIdx.z;

  const float* XP;
  const float* YP = nullptr;
  if (s == 0) {
    XP = sp.x0 + (size_t)img * 384 * 384;
    YP = sp.y0 + (size_t)img * 384 * 384;
  } else {
    XP = sp.ip[s - 1] + (size_t)img * H * W * 2;  // interleaved plane
  }

  const int t = threadIdx.x;
  const int lane = t & 63, wv = t >> 6;
  int cp = (x0 >> 1) + lane;
  cp = cp < W2 - 1 ? cp : W2 - 1;
  const int row0 = by * 16 + wv * 4;

  // Weight pairs QQ[n] = (G[n], G[n-1]), G[-1]=0. All other weight forms
  // derived via op_sel (splat-lo / swap) using G[k] = G[10-k].
  f2 QQ[6];
  QQ[0].x = GW[0]; QQ[0].y = 0.f;
#pragma unroll
  for (int n = 1; n < 6; ++n) { QQ[n].x = GW[n]; QQ[n].y = GW[n - 1]; }

  float ssim_s = 0.f, cs_s = 0.f;

  if (row0 < OH) {
    f2 AU[4] = {}, AW[4] = {}, BU[4] = {}, BW[4] = {};
    const bool noclamp = (row0 + 13 <= H - 1);
    if (s == 0) {
      if (noclamp) vblur<true, false>(XP, YP, row0, W2, H, cp, AU, AW, BU, BW, QQ);
      else         vblur<true, true >(XP, YP, row0, W2, H, cp, AU, AW, BU, BW, QQ);
    } else {
      if (noclamp) vblur<false, false>(XP, YP, row0, W2, H, cp, AU, AW, BU, BW, QQ);
      else         vblur<false, true >(XP, YP, row0, W2, H, cp, AU, AW, BU, BW, QQ);
    }

    // hblur: 2 outputs/lane, 5 two-col shift steps.
    // O.x = sum_k G[k]*V[2c+k], O.y = sum_k G[k]*V[2c+1+k]; contribution of
    // t_j=(e,o)=(V[2c+2j],V[2c+2j+1]): (G[2j],G[2j-1])*e + (G[2j+1],G[2j])*o.
    auto hb = [&QQ](f2 tt) -> f2 {
      f2 h = pk_mul_s1lo(QQ[0], tt);   // j=0: (G0,0)*e
      fma_nh(h, QQ[1], tt);            // j=0: (G1,G0)*o
      tt = wshl1v(tt);
      fma_nl(h, QQ[2], tt);            // j=1: (G2,G1)*e
      fma_nh(h, QQ[3], tt);            // j=1: (G3,G2)*o
      tt = wshl1v(tt);
      fma_nl(h, QQ[4], tt);            // j=2: (G4,G3)*e
      fma_nh(h, QQ[5], tt);            // j=2: (G5,G4)*o
      tt = wshl1v(tt);
      fma_sl(h, QQ[5], tt);            // j=3: (G6,G5)=(G4,G5)=swap(QQ5)
      fma_sh(h, QQ[4], tt);            // j=3: (G7,G6)=(G3,G4)=swap(QQ4)
      tt = wshl1v(tt);
      fma_sl(h, QQ[3], tt);            // j=4: (G8,G7)=swap(QQ3)
      fma_sh(h, QQ[2], tt);            // j=4: (G9,G8)=swap(QQ2)
      tt = wshl1v(tt);
      fma_sl(h, QQ[1], tt);            // j=5: (G10,G9)=swap(QQ1)
      fma_sh(h, QQ[0], tt);            // j=5: (0,G10)=swap(QQ0)
      return h;
    };

    const bool vx = (2 * lane) < tw;
    const bool vy = (2 * lane + 1) < tw;
#pragma unroll
    for (int i = 0; i < 4; ++i) {
      if (row0 + i < OH) {
        f2 bU = hb(AU[i]), bW = hb(AW[i]);
        f2 bU2 = hb(BU[i]), bW2 = hb(BW[i]);
        f2 m2u = pk_mul(bU, bU), m2w = pk_mul(bW, bW);
        f2 Pm = m2u - m2w;           // 4*mu1*mu2
        f2 Qm = m2u + m2w;           // 2*(mu1^2+mu2^2)
        f2 Am = bU2 - bW2;           // 4*E[xy]
        f2 Bm = bU2 + bW2;           // 2*(E[xx]+E[yy])
        float csx = (Am.x - Pm.x + TWO_C2) *
                    __builtin_amdgcn_rcpf(Bm.x - Qm.x + TWO_C2);
        float lx = (Pm.x + TWO_C1) * __builtin_amdgcn_rcpf(Qm.x + TWO_C1);
        float csy = (Am.y - Pm.y + TWO_C2) *
                    __builtin_amdgcn_rcpf(Bm.y - Qm.y + TWO_C2);
        float ly = (Pm.y + TWO_C1) * __builtin_amdgcn_rcpf(Qm.y + TWO_C1);
        if (vx) { cs_s += csx; ssim_s += lx * csx; }
        if (vy) { cs_s += csy; ssim_s += ly * csy; }
      }
    }
  }

  // ---- reduce: wave shuffle -> LDS -> 2 atomics/block ----
#pragma unroll
  for (int off = 32; off > 0; off >>= 1) {
    ssim_s += __shfl_down(ssim_s, off);
    cs_s += __shfl_down(cs_s, off);
  }
  if (lane == 0) { red[0][wv] = ssim_s; red[1][wv] = cs_s; }
  __syncthreads();
  if (t == 0) {
    atomicAdd(&acc[(2 * s + 0) * NIMG + img],
              red[0][0] + red[0][1] + red[0][2] + red[0][3]);
    atomicAdd(&acc[(2 * s + 1) * NIMG + img],
              red[1][0] + red[1][1] + red[1][2] + red[1][3]);
  }
}

// Coalesced pyramid producing u/w-interleaved planes at levels 1..4.
// Each wave owns a 64x16 source tile processed as two 8-row batches.
// lane: c = lane&15 (16 x float4 = 64 cols), r = lane>>4 (4 row-pairs).
// All loads dwordx4 (256B segments per r-group); all stores float4
// (u0,u1,w0,w1) per col-pair. 2x2 reductions via in-lane adds + shfl_xor.
// Block(0,0) zeroes accumulators.
__global__ __launch_bounds__(256) void pyramid_kernel(
    const float* __restrict__ X, const float* __restrict__ Y,
    float* __restrict__ i1, float* __restrict__ i2,
    float* __restrict__ i3, float* __restrict__ i4,
    float* __restrict__ acc) {
  const int img = blockIdx.y;
  const int t = threadIdx.x;
  if (blockIdx.x == 0 && img == 0) {
    for (int i = t; i < 10 * NIMG; i += 256) acc[i] = 0.f;
  }
  const int wv = t >> 6, lane = t & 63;
  const int tidx = blockIdx.x * 4 + wv;     // 0..143
  const int tx = tidx % 6, ty = tidx / 6;   // 6 x 24 tiles of 64x16
  const int r = lane >> 4, c = lane & 15;

  const float* Xs = X + (size_t)img * 384 * 384;
  const float* Ys = Y + (size_t)img * 384 * 384;
  f4* p1 = (f4*)i1 + (size_t)img * 192 * 96;
  f4* p2 = (f4*)i2 + (size_t)img * 96 * 48;
  f4* p3 = (f4*)i3 + (size_t)img * 48 * 24;
  f4* p4 = (f4*)i4 + (size_t)img * 24 * 12;

  float h4u = 0.f, h4w = 0.f;
#pragma unroll
  for (int b = 0; b < 2; ++b) {
    const int gr = ty * 16 + b * 8 + 2 * r;
    const int gc = tx * 64 + 4 * c;
    f4 xu = *(const f4*)&Xs[(size_t)gr * 384 + gc];
    f4 xv = *(const f4*)&Xs[(size_t)(gr + 1) * 384 + gc];
    f4 yu = *(const f4*)&Ys[(size_t)gr * 384 + gc];
    f4 yv = *(const f4*)&Ys[(size_t)(gr + 1) * 384 + gc];
    float ax = 0.25f * (xu.x + xu.y + xv.x + xv.y);   // L1 of X @ C1
    float bx = 0.25f * (xu.z + xu.w + xv.z + xv.w);   // L1 of X @ C1+1
    float ay = 0.25f * (yu.x + yu.y + yv.x + yv.y);
    float by = 0.25f * (yu.z + yu.w + yv.z + yv.w);
    float u0 = ax + ay, u1v = bx + by, w0 = ax - ay, w1v = bx - by;
    {  // L1: row ty*8+4b+r, colpair tx*16+c  (16 lanes x 16B = 256B)
      f4 st; st.x = u0; st.y = u1v; st.z = w0; st.w = w1v;
      p1[(size_t)(ty * 8 + b * 4 + r) * 96 + tx * 16 + c] = st;
    }
    // L2: horizontal in-lane, vertical via r-pair (lane^16).
    float hu = u0 + u1v, hw = w0 + w1v;
    float su = 0.25f * (hu + __shfl_xor(hu, 16));     // L2 @ (R2, tx*16+c)
    float sw = 0.25f * (hw + __shfl_xor(hw, 16));
    float suh = __shfl_xor(su, 1), swh = __shfl_xor(sw, 1);
    if ((r & 1) == 0 && (c & 1) == 0) {
      f4 st; st.x = su; st.y = suh; st.z = sw; st.w = swh;
      p2[(size_t)(ty * 4 + 2 * b + (r >> 1)) * 48 + tx * 8 + (c >> 1)] = st;
    }
    // L3: col pair via lane^1, row pair via lane^32 (r 0<->2).
    float au = su + __shfl_xor(su, 1);
    float aw = sw + __shfl_xor(sw, 1);
    float u3 = 0.25f * (au + __shfl_xor(au, 32));     // L3 @ (ty*2+b, tx*8+(c>>1))
    float w3 = 0.25f * (aw + __shfl_xor(aw, 32));
    float u3h = __shfl_xor(u3, 2), w3h = __shfl_xor(w3, 2);
    if (r == 0 && (c & 3) == 0) {
      f4 st; st.x = u3; st.y = u3h; st.z = w3; st.w = w3h;
      p3[(size_t)(ty * 2 + b) * 24 + tx * 4 + (c >> 2)] = st;
    }
    // L4: col pair via lane^2, row pair across batches (kept in regs).
    float hu4 = u3 + __shfl_xor(u3, 2);
    float hw4 = w3 + __shfl_xor(w3, 2);
    if (b == 0) {
      h4u = hu4; h4w = hw4;
    } else {
      float l4u = 0.25f * (h4u + hu4), l4w = 0.25f * (h4w + hw4);
      float l4uh = __shfl_xor(l4u, 4), l4wh = __shfl_xor(l4w, 4);
      if (r == 0 && (c & 7) == 0) {
        f4 st; st.x = l4u; st.y = l4uh; st.z = l4w; st.w = l4wh;
        p4[(size_t)ty * 12 + tx * 2 + (c >> 3)] = st;
      }
    }
  }
}

// acc layout: acc[s*2+0][img] = ssim sum, acc[s*2+1][img] = cs sum.
__global__ void final_kernel(const float* __restrict__ acc,
                             float* __restrict__ out) {
  __shared__ float prods[NIMG];
  const float wts[5] = {0.0448f, 0.2856f, 0.3001f, 0.2363f, 0.1333f};
  const float inv_npix[5] = {1.f / (374.f * 374.f), 1.f / (182.f * 182.f),
                             1.f / (86.f * 86.f),  1.f / (38.f * 38.f),
                             1.f / (14.f * 14.f)};
  int t = threadIdx.x;
  if (t < NIMG) {
    float p = 1.f;
#pragma unroll
    for (int s = 0; s < 5; ++s) {
      float sum = (s < 4) ? acc[(s * 2 + 1) * NIMG + t]
                          : acc[(s * 2 + 0) * NIMG + t];
      float m = sum * inv_npix[s];
      m = m > 0.f ? m : 0.f;
      p *= powf(m, wts[s]);
    }
    prods[t] = p;
  }
  __syncthreads();
  if (t == 0) {
    float s = 0.f;
    for (int i = 0; i < NIMG; ++i) s += prods[i];
    out[0] = 1.f - s / (float)NIMG;
  }
}

}  // namespace

extern "C" void kernel_launch(void* const* d_in, const int* in_sizes, int n_in,
                              void* d_out, int out_size, void* d_ws,
                              size_t ws_size, hipStream_t stream) {
  const float* X0 = (const float*)d_in[0];
  const float* Y0 = (const float*)d_in[1];
  float* out = (float*)d_out;
  float* ws = (float*)d_ws;

  // Interleaved u/w planes: level L holds 2*H*W floats.
  const size_t L1 = (size_t)NIMG * 192 * 192 * 2;
  const size_t L2 = (size_t)NIMG * 96 * 96 * 2;
  const size_t L3 = (size_t)NIMG * 48 * 48 * 2;
  const size_t L4 = (size_t)NIMG * 24 * 24 * 2;

  float* i1 = ws;
  float* i2 = i1 + L1;
  float* i3 = i2 + L2;
  float* i4 = i3 + L3;
  float* acc = i4 + L4;  // 5*2*96 floats

  pyramid_kernel<<<dim3(36, NIMG), dim3(256), 0, stream>>>(
      X0, Y0, i1, i2, i3, i4, acc);

  SPtrs sp;
  sp.x0 = X0; sp.y0 = Y0;
  sp.ip[0] = i1; sp.ip[1] = i2; sp.ip[2] = i3; sp.ip[3] = i4;

  ssim_all<<<dim3(130, 1, NIMG), dim3(256), 0, stream>>>(sp, acc);

  final_kernel<<<dim3(1), dim3(128), 0, stream>>>(acc, out);
}

// Round 3
// 230.126 us; speedup vs baseline: 1.1106x; 1.0473x over previous
//
#include <hip/hip_runtime.h>
#include <math.h>

// MS-SSIM loss, fp32, (32,3,384,384), 5 scales, win=11 sigma=1.5, VALID.
// R11: full load hoist. R8-R10 invariant: VALU-busy-time ~= 65-75us
// (the issue floor), rest of ssim_all's 116us is per-iteration load
// stalls (per-wave issue fraction stuck at 13-15%). Depth-4 rotating
// prefetch (R10) failed: 3 iterations (~120cy) between issue and use
// vs 200-900cy latency. Fix: stage ALL 14 rows (28 f2 / 14 f4 loads,
// 56 VGPRs) in registers BEFORE the tap loop; wave pays latency once.
// sched_barrier(0) pins the stage against sinking. 32-bit affine
// addressing replaces 64-bit mads. launch_bounds(256,4) -> 128 regs:
// stage 56 + acc 32 + QQ 12 + temps ~15 = ~115. WRITE_SIZE jump would
// mean spill (fallback: shallower staging).

namespace {

constexpr int NIMG = 96;            // B*C = 32*3
constexpr float TWO_C1 = 13.005f;   // 2*(0.01*255)^2
constexpr float TWO_C2 = 117.045f;  // 2*(0.03*255)^2

// gauss(11, sigma=1.5), normalized (matches expf path to fp32 ulp).
__device__ constexpr float GW[11] = {
    0.00102838f, 0.00759875f, 0.03600077f, 0.10936070f, 0.21300553f,
    0.26601172f,
    0.21300553f, 0.10936070f, 0.03600077f, 0.00759875f, 0.00102838f};

typedef float f2 __attribute__((ext_vector_type(2)));
typedef float f4 __attribute__((ext_vector_type(4)));

// ---- VOP3P packed fp32 with op_sel variants ----
// op_sel[i]: half feeding LOW result (0=lo); op_sel_hi[i]: half feeding HIGH.
__device__ __forceinline__ f2 pk_mul(f2 a, f2 b) {
  f2 d;
  asm("v_pk_mul_f32 %0, %1, %2" : "=v"(d) : "v"(a), "v"(b));
  return d;
}
// d = a * splat_lo(b)  (init of hblur chain, j=0 even term)
__device__ __forceinline__ f2 pk_mul_s1lo(f2 a, f2 b) {
  f2 d;
  asm("v_pk_mul_f32 %0, %1, %2 op_sel:[0,0] op_sel_hi:[1,0]"
      : "=v"(d) : "v"(a), "v"(b));
  return d;
}
// d += splat_lo(q) * p   (vblur tap: weight splat from pair reg)
__device__ __forceinline__ void fma_w(f2& d, f2 q, f2 p) {
  asm("v_pk_fma_f32 %0, %1, %2, %0 op_sel:[0,0,0] op_sel_hi:[0,1,1]"
      : "+v"(d) : "v"(q), "v"(p));
}
// d += q * splat_lo(t)
__device__ __forceinline__ void fma_nl(f2& d, f2 q, f2 t) {
  asm("v_pk_fma_f32 %0, %1, %2, %0 op_sel:[0,0,0] op_sel_hi:[1,0,1]"
      : "+v"(d) : "v"(q), "v"(t));
}
// d += q * splat_hi(t)
__device__ __forceinline__ void fma_nh(f2& d, f2 q, f2 t) {
  asm("v_pk_fma_f32 %0, %1, %2, %0 op_sel:[0,1,0] op_sel_hi:[1,1,1]"
      : "+v"(d) : "v"(q), "v"(t));
}
// d += swap(q) * splat_lo(t)
__device__ __forceinline__ void fma_sl(f2& d, f2 q, f2 t) {
  asm("v_pk_fma_f32 %0, %1, %2, %0 op_sel:[1,0,0] op_sel_hi:[0,0,1]"
      : "+v"(d) : "v"(q), "v"(t));
}
// d += swap(q) * splat_hi(t)
__device__ __forceinline__ void fma_sh(f2& d, f2 q, f2 t) {
  asm("v_pk_fma_f32 %0, %1, %2, %0 op_sel:[1,1,0] op_sel_hi:[0,1,1]"
      : "+v"(d) : "v"(q), "v"(t));
}

// lane i <- lane i+1 (wave_shl:1); lane 63 gets 0. HW-verified (R5-R7).
__device__ __forceinline__ float wshl1(float v) {
  return __int_as_float(__builtin_amdgcn_mov_dpp(
      __float_as_int(v), 0x130, 0xF, 0xF, true));
}
__device__ __forceinline__ f2 wshl1v(f2 v) {
  f2 r;
  r.x = wshl1(v.x);
  r.y = wshl1(v.y);
  return r;
}

struct SPtrs {
  const float* x0;
  const float* y0;
  const float* ip[4];  // levels 1..4, u/w interleaved (u0,u1,w0,w1)/colpair
};

// Fully-hoisted vertical blur: all 14 rows staged in registers, THEN the
// tap loop. Wave pays global latency once (28 loads in flight) instead of
// per-row. BASE: two f2 loads/row (X0,Y0), u/w formed in-kernel. !BASE:
// one f4 load/row from the interleaved plane (Pu=v.xy, Pw=v.zw).
template <bool BASE, bool CLAMP>
__device__ __forceinline__ void vblur(const float* __restrict__ XP,
                                      const float* __restrict__ YP, int row0,
                                      int W2, int H, int cp, f2 (&AU)[4],
                                      f2 (&AW)[4], f2 (&BU)[4], f2 (&BW)[4],
                                      const f2 (&QQ)[6]) {
  const f2* PA = (const f2*)XP;
  const f2* PB = (const f2*)YP;
  const f4* PV = (const f4*)XP;
  f2 sa[14], sb[14];
  f4 sv[14];
#pragma unroll
  for (int j = 0; j < 14; ++j) {
    int rin = row0 + j;
    if (CLAMP) rin = rin < H - 1 ? rin : H - 1;
    const int off = rin * W2 + cp;      // 32-bit affine (fits: <= 384*192)
    if (BASE) {
      sa[j] = PA[off];
      sb[j] = PB[off];
    } else {
      sv[j] = PV[off];
    }
  }
  __builtin_amdgcn_sched_barrier(0);    // keep stage loads hoisted
#pragma unroll
  for (int j = 0; j < 14; ++j) {
    f2 Pu, Pw;
    if (BASE) {
      f2 pa = sa[j], pb = sb[j];
      Pu = pa + pb;
      Pw = pa - pb;
    } else {
      f4 v = sv[j];
      Pu.x = v.x; Pu.y = v.y;
      Pw.x = v.z; Pw.y = v.w;
    }
    f2 Qu = pk_mul(Pu, Pu), Qw = pk_mul(Pw, Pw);
#pragma unroll
    for (int i = 0; i < 4; ++i) {
      const int k = j - i;
      if (k >= 0 && k <= 10) {
        const int qi = k <= 5 ? k : 10 - k;     // G[k] = QQ[qi].x
        fma_w(AU[i], QQ[qi], Pu);
        fma_w(AW[i], QQ[qi], Pw);
        fma_w(BU[i], QQ[qi], Qu);
        fma_w(BW[i], QQ[qi], Qw);
      }
    }
  }
}

// Tile: 64 lanes x 2 cols = 128 input cols -> up to 118 outputs; 4 output
// rows per wave, 4 waves stacked = 16 rows/block.
// Grid/img: s0 4x24=96, s1 2x12=24, s2 6, s3 3, s4 1 (total 130).
__global__ __launch_bounds__(256, 4) void ssim_all(SPtrs sp,
                                                   float* __restrict__ acc) {
  __shared__ float red[2][4];

  const int tile = blockIdx.x;
  int s;
  if (tile < 96) s = 0;
  else if (tile < 120) s = 1;
  else if (tile < 126) s = 2;
  else if (tile < 129) s = 3;
  else s = 4;
  const int tstart[5] = {0, 96, 120, 126, 129};
  const int HH[5] = {384, 192, 96, 48, 24};
  const int NTX[5] = {4, 2, 1, 1, 1};
  const int TWM[5] = {94, 92, 86, 38, 14};
  const int lt = tile - tstart[s];
  const int H = HH[s], W = H, OH = H - 10, OW = W - 10, W2 = W >> 1;
  const int tx = lt % NTX[s], by = lt / NTX[s];
  const int x0 = tx * TWM[s];
  const int tw = (TWM[s] < OW - x0) ? TWM[s] : OW - x0;
  const int img = blockIdx.z;

  const float* XP;
  const float* YP = nullptr;
  if (s == 0) {
    XP = sp.x0 + (size_t)img * 384 * 384;
    YP = sp.y0 + (size_t)img * 384 * 384;
  } else {
    XP = sp.ip[s - 1] + (size_t)img * H * W * 2;  // interleaved plane
  }

  const int t = threadIdx.x;
  const int lane = t & 63, wv = t >> 6;
  int cp = (x0 >> 1) + lane;
  cp = cp < W2 - 1 ? cp : W2 - 1;
  const int row0 = by * 16 + wv * 4;

  // Weight pairs QQ[n] = (G[n], G[n-1]), G[-1]=0. All other weight forms
  // derived via op_sel (splat-lo / swap) using G[k] = G[10-k].
  f2 QQ[6];
  QQ[0].x = GW[0]; QQ[0].y = 0.f;
#pragma unroll
  for (int n = 1; n < 6; ++n) { QQ[n].x = GW[n]; QQ[n].y = GW[n - 1]; }

  float ssim_s = 0.f, cs_s = 0.f;

  if (row0 < OH) {
    f2 AU[4] = {}, AW[4] = {}, BU[4] = {}, BW[4] = {};
    const bool noclamp = (row0 + 13 <= H - 1);
    if (s == 0) {
      if (noclamp) vblur<true, false>(XP, YP, row0, W2, H, cp, AU, AW, BU, BW, QQ);
      else         vblur<true, true >(XP, YP, row0, W2, H, cp, AU, AW, BU, BW, QQ);
    } else {
      if (noclamp) vblur<false, false>(XP, YP, row0, W2, H, cp, AU, AW, BU, BW, QQ);
      else         vblur<false, true >(XP, YP, row0, W2, H, cp, AU, AW, BU, BW, QQ);
    }

    // hblur: 2 outputs/lane, 5 two-col shift steps.
    // O.x = sum_k G[k]*V[2c+k], O.y = sum_k G[k]*V[2c+1+k]; contribution of
    // t_j=(e,o)=(V[2c+2j],V[2c+2j+1]): (G[2j],G[2j-1])*e + (G[2j+1],G[2j])*o.
    auto hb = [&QQ](f2 tt) -> f2 {
      f2 h = pk_mul_s1lo(QQ[0], tt);   // j=0: (G0,0)*e
      fma_nh(h, QQ[1], tt);            // j=0: (G1,G0)*o
      tt = wshl1v(tt);
      fma_nl(h, QQ[2], tt);            // j=1: (G2,G1)*e
      fma_nh(h, QQ[3], tt);            // j=1: (G3,G2)*o
      tt = wshl1v(tt);
      fma_nl(h, QQ[4], tt);            // j=2: (G4,G3)*e
      fma_nh(h, QQ[5], tt);            // j=2: (G5,G4)*o
      tt = wshl1v(tt);
      fma_sl(h, QQ[5], tt);            // j=3: (G6,G5)=(G4,G5)=swap(QQ5)
      fma_sh(h, QQ[4], tt);            // j=3: (G7,G6)=(G3,G4)=swap(QQ4)
      tt = wshl1v(tt);
      fma_sl(h, QQ[3], tt);            // j=4: (G8,G7)=swap(QQ3)
      fma_sh(h, QQ[2], tt);            // j=4: (G9,G8)=swap(QQ2)
      tt = wshl1v(tt);
      fma_sl(h, QQ[1], tt);            // j=5: (G10,G9)=swap(QQ1)
      fma_sh(h, QQ[0], tt);            // j=5: (0,G10)=swap(QQ0)
      return h;
    };

    const bool vx = (2 * lane) < tw;
    const bool vy = (2 * lane + 1) < tw;
#pragma unroll
    for (int i = 0; i < 4; ++i) {
      if (row0 + i < OH) {
        f2 bU = hb(AU[i]), bW = hb(AW[i]);
        f2 bU2 = hb(BU[i]), bW2 = hb(BW[i]);
        f2 m2u = pk_mul(bU, bU), m2w = pk_mul(bW, bW);
        f2 Pm = m2u - m2w;           // 4*mu1*mu2
        f2 Qm = m2u + m2w;           // 2*(mu1^2+mu2^2)
        f2 Am = bU2 - bW2;           // 4*E[xy]
        f2 Bm = bU2 + bW2;           // 2*(E[xx]+E[yy])
        float csx = (Am.x - Pm.x + TWO_C2) *
                    __builtin_amdgcn_rcpf(Bm.x - Qm.x + TWO_C2);
        float lx = (Pm.x + TWO_C1) * __builtin_amdgcn_rcpf(Qm.x + TWO_C1);
        float csy = (Am.y - Pm.y + TWO_C2) *
                    __builtin_amdgcn_rcpf(Bm.y - Qm.y + TWO_C2);
        float ly = (Pm.y + TWO_C1) * __builtin_amdgcn_rcpf(Qm.y + TWO_C1);
        if (vx) { cs_s += csx; ssim_s += lx * csx; }
        if (vy) { cs_s += csy; ssim_s += ly * csy; }
      }
    }
  }

  // ---- reduce: wave shuffle -> LDS -> 2 atomics/block ----
#pragma unroll
  for (int off = 32; off > 0; off >>= 1) {
    ssim_s += __shfl_down(ssim_s, off);
    cs_s += __shfl_down(cs_s, off);
  }
  if (lane == 0) { red[0][wv] = ssim_s; red[1][wv] = cs_s; }
  __syncthreads();
  if (t == 0) {
    atomicAdd(&acc[(2 * s + 0) * NIMG + img],
              red[0][0] + red[0][1] + red[0][2] + red[0][3]);
    atomicAdd(&acc[(2 * s + 1) * NIMG + img],
              red[1][0] + red[1][1] + red[1][2] + red[1][3]);
  }
}

// Coalesced pyramid producing u/w-interleaved planes at levels 1..4.
// Each wave owns a 64x16 source tile processed as two 8-row batches.
// lane: c = lane&15 (16 x float4 = 64 cols), r = lane>>4 (4 row-pairs).
// All loads dwordx4 (256B segments per r-group); all stores float4
// (u0,u1,w0,w1) per col-pair. 2x2 reductions via in-lane adds + shfl_xor.
// Block(0,0) zeroes accumulators.
__global__ __launch_bounds__(256) void pyramid_kernel(
    const float* __restrict__ X, const float* __restrict__ Y,
    float* __restrict__ i1, float* __restrict__ i2,
    float* __restrict__ i3, float* __restrict__ i4,
    float* __restrict__ acc) {
  const int img = blockIdx.y;
  const int t = threadIdx.x;
  if (blockIdx.x == 0 && img == 0) {
    for (int i = t; i < 10 * NIMG; i += 256) acc[i] = 0.f;
  }
  const int wv = t >> 6, lane = t & 63;
  const int tidx = blockIdx.x * 4 + wv;     // 0..143
  const int tx = tidx % 6, ty = tidx / 6;   // 6 x 24 tiles of 64x16
  const int r = lane >> 4, c = lane & 15;

  const float* Xs = X + (size_t)img * 384 * 384;
  const float* Ys = Y + (size_t)img * 384 * 384;
  f4* p1 = (f4*)i1 + (size_t)img * 192 * 96;
  f4* p2 = (f4*)i2 + (size_t)img * 96 * 48;
  f4* p3 = (f4*)i3 + (size_t)img * 48 * 24;
  f4* p4 = (f4*)i4 + (size_t)img * 24 * 12;

  float h4u = 0.f, h4w = 0.f;
#pragma unroll
  for (int b = 0; b < 2; ++b) {
    const int gr = ty * 16 + b * 8 + 2 * r;
    const int gc = tx * 64 + 4 * c;
    f4 xu = *(const f4*)&Xs[(size_t)gr * 384 + gc];
    f4 xv = *(const f4*)&Xs[(size_t)(gr + 1) * 384 + gc];
    f4 yu = *(const f4*)&Ys[(size_t)gr * 384 + gc];
    f4 yv = *(const f4*)&Ys[(size_t)(gr + 1) * 384 + gc];
    float ax = 0.25f * (xu.x + xu.y + xv.x + xv.y);   // L1 of X @ C1
    float bx = 0.25f * (xu.z + xu.w + xv.z + xv.w);   // L1 of X @ C1+1
    float ay = 0.25f * (yu.x + yu.y + yv.x + yv.y);
    float by = 0.25f * (yu.z + yu.w + yv.z + yv.w);
    float u0 = ax + ay, u1v = bx + by, w0 = ax - ay, w1v = bx - by;
    {  // L1: row ty*8+4b+r, colpair tx*16+c  (16 lanes x 16B = 256B)
      f4 st; st.x = u0; st.y = u1v; st.z = w0; st.w = w1v;
      p1[(size_t)(ty * 8 + b * 4 + r) * 96 + tx * 16 + c] = st;
    }
    // L2: horizontal in-lane, vertical via r-pair (lane^16).
    float hu = u0 + u1v, hw = w0 + w1v;
    float su = 0.25f * (hu + __shfl_xor(hu, 16));     // L2 @ (R2, tx*16+c)
    float sw = 0.25f * (hw + __shfl_xor(hw, 16));
    float suh = __shfl_xor(su, 1), swh = __shfl_xor(sw, 1);
    if ((r & 1) == 0 && (c & 1) == 0) {
      f4 st; st.x = su; st.y = suh; st.z = sw; st.w = swh;
      p2[(size_t)(ty * 4 + 2 * b + (r >> 1)) * 48 + tx * 8 + (c >> 1)] = st;
    }
    // L3: col pair via lane^1, row pair via lane^32 (r 0<->2).
    float au = su + __shfl_xor(su, 1);
    float aw = sw + __shfl_xor(sw, 1);
    float u3 = 0.25f * (au + __shfl_xor(au, 32));     // L3 @ (ty*2+b, tx*8+(c>>1))
    float w3 = 0.25f * (aw + __shfl_xor(aw, 32));
    float u3h = __shfl_xor(u3, 2), w3h = __shfl_xor(w3, 2);
    if (r == 0 && (c & 3) == 0) {
      f4 st; st.x = u3; st.y = u3h; st.z = w3; st.w = w3h;
      p3[(size_t)(ty * 2 + b) * 24 + tx * 4 + (c >> 2)] = st;
    }
    // L4: col pair via lane^2, row pair across batches (kept in regs).
    float hu4 = u3 + __shfl_xor(u3, 2);
    float hw4 = w3 + __shfl_xor(w3, 2);
    if (b == 0) {
      h4u = hu4; h4w = hw4;
    } else {
      float l4u = 0.25f * (h4u + hu4), l4w = 0.25f * (h4w + hw4);
      float l4uh = __shfl_xor(l4u, 4), l4wh = __shfl_xor(l4w, 4);
      if (r == 0 && (c & 7) == 0) {
        f4 st; st.x = l4u; st.y = l4uh; st.z = l4w; st.w = l4wh;
        p4[(size_t)ty * 12 + tx * 2 + (c >> 3)] = st;
      }
    }
  }
}

// acc layout: acc[s*2+0][img] = ssim sum, acc[s*2+1][img] = cs sum.
__global__ void final_kernel(const float* __restrict__ acc,
                             float* __restrict__ out) {
  __shared__ float prods[NIMG];
  const float wts[5] = {0.0448f, 0.2856f, 0.3001f, 0.2363f, 0.1333f};
  const float inv_npix[5] = {1.f / (374.f * 374.f), 1.f / (182.f * 182.f),
                             1.f / (86.f * 86.f),  1.f / (38.f * 38.f),
                             1.f / (14.f * 14.f)};
  int t = threadIdx.x;
  if (t < NIMG) {
    float p = 1.f;
#pragma unroll
    for (int s = 0; s < 5; ++s) {
      float sum = (s < 4) ? acc[(s * 2 + 1) * NIMG + t]
                          : acc[(s * 2 + 0) * NIMG + t];
      float m = sum * inv_npix[s];
      m = m > 0.f ? m : 0.f;
      p *= powf(m, wts[s]);
    }
    prods[t] = p;
  }
  __syncthreads();
  if (t == 0) {
    float s = 0.f;
    for (int i = 0; i < NIMG; ++i) s += prods[i];
    out[0] = 1.f - s / (float)NIMG;
  }
}

}  // namespace

extern "C" void kernel_launch(void* const* d_in, const int* in_sizes, int n_in,
                              void* d_out, int out_size, void* d_ws,
                              size_t ws_size, hipStream_t stream) {
  const float* X0 = (const float*)d_in[0];
  const float* Y0 = (const float*)d_in[1];
  float* out = (float*)d_out;
  float* ws = (float*)d_ws;

  // Interleaved u/w planes: level L holds 2*H*W floats.
  const size_t L1 = (size_t)NIMG * 192 * 192 * 2;
  const size_t L2 = (size_t)NIMG * 96 * 96 * 2;
  const size_t L3 = (size_t)NIMG * 48 * 48 * 2;
  const size_t L4 = (size_t)NIMG * 24 * 24 * 2;

  float* i1 = ws;
  float* i2 = i1 + L1;
  float* i3 = i2 + L2;
  float* i4 = i3 + L3;
  float* acc = i4 + L4;  // 5*2*96 floats

  pyramid_kernel<<<dim3(36, NIMG), dim3(256), 0, stream>>>(
      X0, Y0, i1, i2, i3, i4, acc);

  SPtrs sp;
  sp.x0 = X0; sp.y0 = Y0;
  sp.ip[0] = i1; sp.ip[1] = i2; sp.ip[2] = i3; sp.ip[3] = i4;

  ssim_all<<<dim3(130, 1, NIMG), dim3(256), 0, stream>>>(sp, acc);

  final_kernel<<<dim3(1), dim3(128), 0, stream>>>(acc, out);
}